// Round 3
// baseline (297.872 us; speedup 1.0000x reference)
//
#include <hip/hip_runtime.h>

// Problem constants (B, C=1, H, W) from the reference.
#define H_ 1024
#define W_ 1024
#define B_ 16
#define TH 8                   // output rows per block (STEPS=14 fully unrolls; 22 spilled - r3)
#define STEPS (TH + 6)         // input rows streamed (halo 3 each side)
#define GX (H_ / TH)           // 128 y-tiles per image
#define NBLK (GX * B_)         // 2048 blocks
#define NACC 13
#define PITCH 272              // per-wave LDS row pitch (floats): 4L | 256 | 4R | slack to 272
#define RING 6                 // LDS row-ring slots per wave (must be > PF)
#define PF 4                   // prefetch depth (rows in flight)

// partials layout (SoA): partials[j * NBLK + bid]
//  j: 0=sum_pred, then k=3,5,7: {1,5,9}=sum_dil {2,6,10}=sum_p*dil
//                               {3,7,11}=sum_ero {4,8,12}=sum_p*ero

// r9: RING-STAGED pipeline (T3/T4 pattern), 4 blocks/CU.
//   r8 post-mortem: removing the barrier was neutral (51us, VALUBusy 34%) ->
//   the stall is the bulk vmcnt(0) pipeline-fill itself + only 2 waves/SIMD
//   (58KB LDS). Fix both: per-wave 6-slot row ring (25.7KB LDS -> 4 blocks/CU
//   at VGPR=128 = 4 waves/SIMD), counted vmcnt(8) per step (2 ops x PF=4 rows
//   in flight, never drained to 0 in steady state). Wave-local halo staging
//   (r8, verified exact) kept; no hot-path __syncthreads.
//   vmcnt retires IN ORDER (m135), so "8 youngest = rows s+1..s+PF" holds;
//   pred loads issued first are oldest -> complete by step 0's wait.
// Algebra (verified r2): h0/h3/h5/h7 per row, output row y = t-3:
//   k3 = op(h3[y], h0[y+/-1]); k5 = op(h5[y], h3[y+/-1], h0[y+/-2]);
//   k7 = op(h7[y], h5[y+/-1], h5[y+/-2], h0[y+/-3])
// Geodesic border == clamped-index border -> exact.

__device__ __forceinline__ void gl2lds16(const float* g, float* l) {
  __builtin_amdgcn_global_load_lds(
      (const __attribute__((address_space(1))) void*)g,
      (__attribute__((address_space(3))) void*)l,
      16, 0, 0);
}
__device__ __forceinline__ void gl2lds4(const float* g, float* l) {
  __builtin_amdgcn_global_load_lds(
      (const __attribute__((address_space(1))) void*)g,
      (__attribute__((address_space(3))) void*)l,
      4, 0, 0);
}

// counted vmcnt wait; n is compile-time constant after full unroll
__device__ __forceinline__ void waitv_imm(int n) {
  if (n >= 8)      asm volatile("s_waitcnt vmcnt(8)" ::: "memory");
  else if (n == 6) asm volatile("s_waitcnt vmcnt(6)" ::: "memory");
  else if (n == 4) asm volatile("s_waitcnt vmcnt(4)" ::: "memory");
  else if (n == 2) asm volatile("s_waitcnt vmcnt(2)" ::: "memory");
  else             asm volatile("s_waitcnt vmcnt(0)" ::: "memory");
  __builtin_amdgcn_sched_barrier(0);
}

__global__ __launch_bounds__(256, 4) void k_partials(const float* __restrict__ pred,
                                                     const float* __restrict__ tch,
                                                     float* __restrict__ partials) {
  __shared__ float tbuf[4 * RING * PITCH];   // 4 waves x 6 slots x 272 x 4B = 25.5KB -> 4 blocks/CU
  __shared__ float red[4][NACC];

  const int tid = threadIdx.x;
  // XCD swizzle (r6, FETCH 90->67MB): consecutive same-XCD blocks (n%8 fixed)
  // get consecutive y-tiles -> halo rows hit that XCD's L2.
  const int n     = blockIdx.y * gridDim.x + blockIdx.x;
  const int b     = n >> 7;                              // image (gridDim.x == 128)
  const int ytile = (n & 7) * 16 + ((n >> 3) & 15);      // bijective 0..127
  const int y0    = ytile * TH;
  const int x0    = tid * 4;
  const int wv    = tid >> 6;
  const int lane  = tid & 63;
  const float* tb = tch  + (size_t)b * (H_ * W_);
  const float* pb = pred + (size_t)b * (H_ * W_);

  float* seg0 = &tbuf[wv * (RING * PITCH)];

  // wave-uniform staging parameters (x-clamped at image edges; clamped-in
  // garbage floats are exactly the ones overridden by the a[] edge fixup)
  const int srcA = (wv == 0) ? 0 : -4;      // global col delta vs x0 for load A
  const int dstA = (wv == 0) ? 4 : 0;       // segment float base for load A
  const int srcB = (wv == 3) ? 960 : (wv * 256 + 204);   // absolute col, lane 0
  const int dstB = (wv == 3) ? 196 : 208;

  // ---- pred loads first (oldest in vmcnt order; retired by step 0's wait)
  float4 pv[TH];
#pragma unroll
  for (int j = 0; j < TH; ++j)
    pv[j] = *reinterpret_cast<const float4*>(pb + (size_t)(y0 + j) * W_ + x0);
  asm volatile("" ::: "memory");   // pin pred-load issue before the stage stream

  // ---- ring prologue: issue stages for rows 0..PF-1
#pragma unroll
  for (int s = 0; s < PF; ++s) {
    const int t    = y0 + s - 3;
    const int trow = t < 0 ? 0 : (t >= H_ ? H_ - 1 : t);
    const float* rowp = tb + (size_t)trow * W_;
    float* dst = seg0 + (s % RING) * PITCH;
    gl2lds16(rowp + x0 + srcA, dst + dstA);
    gl2lds4 (rowp + srcB + lane, dst + dstB);
  }

  // ---- main loop: per-step {issue stage(s+PF) || wait row s || compute row s}
  float acc[NACC];
#pragma unroll
  for (int j = 0; j < NACC; j++) acc[j] = 0.f;

  float h0q[7][4];
  float h3M[5][4], h3N[5][4];
  float h5M[6][4], h5N[6][4];
  float h7M[4][4], h7N[4][4];

#pragma unroll
  for (int s = 0; s < STEPS; ++s) {
    if (s + PF < STEPS) {
      const int t    = y0 + (s + PF) - 3;
      const int trow = t < 0 ? 0 : (t >= H_ ? H_ - 1 : t);
      const float* rowp = tb + (size_t)trow * W_;
      float* dst = seg0 + ((s + PF) % RING) * PITCH;
      gl2lds16(rowp + x0 + srcA, dst + dstA);
      gl2lds4 (rowp + srcB + lane, dst + dstB);
    }
    // rows s+1..min(s+PF,13) still in flight (2 ops each); row s must be done
    waitv_imm(s + PF < STEPS ? 2 * PF : 2 * (STEPS - 1 - s));

    // a[0..11] = cols x0-4 .. x0+7 (3x ds_read_b128; 16B-aligned)
    const float4* t4 = reinterpret_cast<const float4*>(seg0 + (s % RING) * PITCH + lane * 4);
    const float4 A0 = t4[0], A1 = t4[1], A2 = t4[2];
    float a[12] = {A0.x, A0.y, A0.z, A0.w, A1.x, A1.y, A1.z, A1.w, A2.x, A2.y, A2.z, A2.w};
    if (tid == 0)   { a[0] = a[1] = a[2]  = a[3]  = a[4]; }   // x-clamp (exact, r5-verified)
    if (tid == 255) { a[8] = a[9] = a[10] = a[11] = a[7]; }

    float QM[8], QN[8];
#pragma unroll
    for (int i = 1; i <= 7; ++i) {
      QM[i] = fmaxf(fmaxf(a[i], a[i + 1]), a[i + 2]);   // v_max3
      QN[i] = fminf(fminf(a[i], a[i + 1]), a[i + 2]);   // v_min3
    }
#pragma unroll
    for (int c = 0; c < 4; ++c) {
      h0q[s % 7][c] = a[c + 4];
      h3M[s % 5][c] = QM[c + 3];
      h3N[s % 5][c] = QN[c + 3];
      h5M[s % 6][c] = fmaxf(QM[c + 2], QM[c + 4]);
      h5N[s % 6][c] = fminf(QN[c + 2], QN[c + 4]);
      h7M[s % 4][c] = fmaxf(fmaxf(QM[c + 1], QM[c + 4]), a[c + 7]);
      h7N[s % 4][c] = fminf(fminf(QN[c + 1], QN[c + 4]), a[c + 7]);
    }

    if (s >= 6) {
      const float4 pq = pv[s - 6];
      const float p[4] = {pq.x, pq.y, pq.z, pq.w};
#pragma unroll
      for (int c = 0; c < 4; ++c) {
        const float d3v = fmaxf(fmaxf(h3M[(s + 2) % 5][c], h0q[(s + 3) % 7][c]), h0q[(s + 5) % 7][c]);
        const float e3v = fminf(fminf(h3N[(s + 2) % 5][c], h0q[(s + 3) % 7][c]), h0q[(s + 5) % 7][c]);

        float d5v = fmaxf(fmaxf(h5M[(s + 3) % 6][c], h3M[(s + 1) % 5][c]), h3M[(s + 3) % 5][c]);
        d5v = fmaxf(fmaxf(d5v, h0q[(s + 2) % 7][c]), h0q[(s + 6) % 7][c]);
        float e5v = fminf(fminf(h5N[(s + 3) % 6][c], h3N[(s + 1) % 5][c]), h3N[(s + 3) % 5][c]);
        e5v = fminf(fminf(e5v, h0q[(s + 2) % 7][c]), h0q[(s + 6) % 7][c]);

        float d7v = fmaxf(fmaxf(h7M[(s + 1) % 4][c], h5M[(s + 2) % 6][c]), h5M[(s + 4) % 6][c]);
        d7v = fmaxf(fmaxf(d7v, h5M[(s + 1) % 6][c]), h5M[(s + 5) % 6][c]);
        d7v = fmaxf(fmaxf(d7v, h0q[(s + 1) % 7][c]), h0q[s % 7][c]);
        float e7v = fminf(fminf(h7N[(s + 1) % 4][c], h5N[(s + 2) % 6][c]), h5N[(s + 4) % 6][c]);
        e7v = fminf(fminf(e7v, h5N[(s + 1) % 6][c]), h5N[(s + 5) % 6][c]);
        e7v = fminf(fminf(e7v, h0q[(s + 1) % 7][c]), h0q[s % 7][c]);

        acc[0]  += p[c];
        acc[1]  += d3v;  acc[2]  = fmaf(p[c], d3v, acc[2]);
        acc[3]  += e3v;  acc[4]  = fmaf(p[c], e3v, acc[4]);
        acc[5]  += d5v;  acc[6]  = fmaf(p[c], d5v, acc[6]);
        acc[7]  += e5v;  acc[8]  = fmaf(p[c], e5v, acc[8]);
        acc[9]  += d7v;  acc[10] = fmaf(p[c], d7v, acc[10]);
        acc[11] += e7v;  acc[12] = fmaf(p[c], e7v, acc[12]);
      }
    }
  }

  // wave (64-lane) shuffle reduction, then cross-wave via LDS
#pragma unroll
  for (int j = 0; j < NACC; j++) {
    float v = acc[j];
#pragma unroll
    for (int off = 32; off > 0; off >>= 1) v += __shfl_down(v, off, 64);
    acc[j] = v;
  }
  if (lane == 0) {
#pragma unroll
    for (int j = 0; j < NACC; j++) red[wv][j] = acc[j];
  }
  __syncthreads();
  if (tid == 0) {
    const int bid = n;   // any bijective block id
#pragma unroll
    for (int j = 0; j < NACC; j++)
      partials[j * NBLK + bid] = red[0][j] + red[1][j] + red[2][j] + red[3][j];
  }
}

__global__ __launch_bounds__(256) void k_final(const float* __restrict__ partials,
                                               float* __restrict__ out) {
  const int tid = threadIdx.x;
  double acc[NACC];
#pragma unroll
  for (int j = 0; j < NACC; j++) acc[j] = 0.0;
#pragma unroll
  for (int k = 0; k < NBLK / 256; k++) {
#pragma unroll
    for (int j = 0; j < NACC; j++)
      acc[j] += (double)partials[j * NBLK + tid + k * 256];   // coalesced, independent
  }
#pragma unroll
  for (int j = 0; j < NACC; j++) {
#pragma unroll
    for (int off = 32; off > 0; off >>= 1) acc[j] += __shfl_down(acc[j], off, 64);
  }
  __shared__ double red[4][NACC];
  const int lane = tid & 63, wv = tid >> 6;
  if (lane == 0) {
#pragma unroll
    for (int j = 0; j < NACC; j++) red[wv][j] = acc[j];
  }
  __syncthreads();
  if (tid == 0) {
    double t_[NACC];
#pragma unroll
    for (int j = 0; j < NACC; j++) t_[j] = red[0][j] + red[1][j] + red[2][j] + red[3][j];
    const double Sp = t_[0];
    double total = 0.0;
#pragma unroll
    for (int k = 0; k < 3; k++) {
      const double Sd = t_[1 + 4 * k], Id = t_[2 + 4 * k];
      const double Se = t_[3 + 4 * k], Ie = t_[4 + 4 * k];
      double cd = Sp + Sd; if (cd < 1e-7) cd = 1e-7;
      double ce = Sp + Se; if (ce < 1e-7) ce = 1e-7;
      total += (1.0 - 2.0 * Id / cd) * (Sd > 0.0 ? 1.0 : 0.0);
      total += (1.0 - 2.0 * Ie / ce) * (Se > 0.0 ? 1.0 : 0.0);
    }
    out[0] = (float)(total / 3.0);
  }
}

extern "C" void kernel_launch(void* const* d_in, const int* in_sizes, int n_in,
                              void* d_out, int out_size, void* d_ws, size_t ws_size,
                              hipStream_t stream) {
  const float* pred = (const float*)d_in[0];  // pred_student_prob
  const float* tch  = (const float*)d_in[1];  // teacher_prob
  float* partials = (float*)d_ws;             // NACC * NBLK floats; fully written each launch

  k_partials<<<dim3(GX, B_), 256, 0, stream>>>(pred, tch, partials);
  k_final<<<1, 256, 0, stream>>>(partials, (float*)d_out);
}

// Round 4
// 160.386 us; speedup vs baseline: 1.8572x; 1.8572x over previous
//
#include <hip/hip_runtime.h>

// Problem constants (B, C=1, H, W) from the reference.
#define H_ 1024
#define W_ 1024
#define B_ 16
#define TH 8                   // output rows per block (STEPS=14 fully unrolls; 22 spilled - r3)
#define STEPS (TH + 6)         // input rows streamed (halo 3 each side)
#define GX (H_ / TH)           // 128 y-tiles per image
#define NBLK (GX * B_)         // 2048 blocks
#define NACC 13
#define PITCH 272              // per-wave LDS row pitch (floats): 4L | 256 | 4R | slack to 272
#define RING 6                 // LDS row-ring slots per wave (must be > PF)
#define PF 4                   // prefetch depth (rows in flight)

// partials layout (SoA): partials[j * NBLK + bid]
//  j: 0=sum_pred, then k=3,5,7: {1,5,9}=sum_dil {2,6,10}=sum_p*dil
//                               {3,7,11}=sum_ero {4,8,12}=sum_p*ero

// r10 = r9 ring pipeline, WITHOUT the __launch_bounds__ min-waves clamp.
//   r9 post-mortem: __launch_bounds__(256,4) clamps the allocator to 64 VGPR
//   on this compiler (r7: same, VGPR=64 + 468MB scratch; r9: VGPR=64 + 461MB
//   scratch). Body needs ~120 live regs -> catastrophic spill; the ring
//   theory never got tested. Plain __launch_bounds__(256) allocates 128
//   (r6/r8, zero spill), and 128 VGPR already gives 4 waves/SIMD; LDS 26KB
//   allows 6 blocks/CU -> residency VGPR-bound at 4 blocks/CU = 16 waves/CU,
//   2x r6/r8.
// Ring structure (r9): per-wave 6-slot row ring, counted vmcnt(8) per step
//   (2 stage ops x PF=4 rows in flight; exact drain 6/4/2/0 in the tail).
//   Wave-local halo staging (r8, verified exact); no hot-path __syncthreads.
//   vmcnt retires IN ORDER (m135); pred loads issued first are oldest ->
//   retired by step 0's wait.
// Algebra (verified r2): h0/h3/h5/h7 per row, output row y = t-3:
//   k3 = op(h3[y], h0[y+/-1]); k5 = op(h5[y], h3[y+/-1], h0[y+/-2]);
//   k7 = op(h7[y], h5[y+/-1], h5[y+/-2], h0[y+/-3])
// Geodesic border == clamped-index border -> exact.

__device__ __forceinline__ void gl2lds16(const float* g, float* l) {
  __builtin_amdgcn_global_load_lds(
      (const __attribute__((address_space(1))) void*)g,
      (__attribute__((address_space(3))) void*)l,
      16, 0, 0);
}
__device__ __forceinline__ void gl2lds4(const float* g, float* l) {
  __builtin_amdgcn_global_load_lds(
      (const __attribute__((address_space(1))) void*)g,
      (__attribute__((address_space(3))) void*)l,
      4, 0, 0);
}

// counted vmcnt wait; n is compile-time constant after full unroll
__device__ __forceinline__ void waitv_imm(int n) {
  if (n >= 8)      asm volatile("s_waitcnt vmcnt(8)" ::: "memory");
  else if (n == 6) asm volatile("s_waitcnt vmcnt(6)" ::: "memory");
  else if (n == 4) asm volatile("s_waitcnt vmcnt(4)" ::: "memory");
  else if (n == 2) asm volatile("s_waitcnt vmcnt(2)" ::: "memory");
  else             asm volatile("s_waitcnt vmcnt(0)" ::: "memory");
  __builtin_amdgcn_sched_barrier(0);
}

__global__ __launch_bounds__(256) void k_partials(const float* __restrict__ pred,
                                                  const float* __restrict__ tch,
                                                  float* __restrict__ partials) {
  __shared__ float tbuf[4 * RING * PITCH];   // 4 waves x 6 slots x 272 x 4B = 25.5KB
  __shared__ float red[4][NACC];

  const int tid = threadIdx.x;
  // XCD swizzle (r6, FETCH 90->67MB): consecutive same-XCD blocks (n%8 fixed)
  // get consecutive y-tiles -> halo rows hit that XCD's L2.
  const int n     = blockIdx.y * gridDim.x + blockIdx.x;
  const int b     = n >> 7;                              // image (gridDim.x == 128)
  const int ytile = (n & 7) * 16 + ((n >> 3) & 15);      // bijective 0..127
  const int y0    = ytile * TH;
  const int x0    = tid * 4;
  const int wv    = tid >> 6;
  const int lane  = tid & 63;
  const float* tb = tch  + (size_t)b * (H_ * W_);
  const float* pb = pred + (size_t)b * (H_ * W_);

  float* seg0 = &tbuf[wv * (RING * PITCH)];

  // wave-uniform staging parameters (x-clamped at image edges; clamped-in
  // garbage floats are exactly the ones overridden by the a[] edge fixup)
  const int srcA = (wv == 0) ? 0 : -4;      // global col delta vs x0 for load A
  const int dstA = (wv == 0) ? 4 : 0;       // segment float base for load A
  const int srcB = (wv == 3) ? 960 : (wv * 256 + 204);   // absolute col, lane 0
  const int dstB = (wv == 3) ? 196 : 208;

  // ---- pred loads first (oldest in vmcnt order; retired by step 0's wait)
  float4 pv[TH];
#pragma unroll
  for (int j = 0; j < TH; ++j)
    pv[j] = *reinterpret_cast<const float4*>(pb + (size_t)(y0 + j) * W_ + x0);
  asm volatile("" ::: "memory");   // pin pred-load issue before the stage stream

  // ---- ring prologue: issue stages for rows 0..PF-1
#pragma unroll
  for (int s = 0; s < PF; ++s) {
    const int t    = y0 + s - 3;
    const int trow = t < 0 ? 0 : (t >= H_ ? H_ - 1 : t);
    const float* rowp = tb + (size_t)trow * W_;
    float* dst = seg0 + (s % RING) * PITCH;
    gl2lds16(rowp + x0 + srcA, dst + dstA);
    gl2lds4 (rowp + srcB + lane, dst + dstB);
  }

  // ---- main loop: per-step {issue stage(s+PF) || wait row s || compute row s}
  float acc[NACC];
#pragma unroll
  for (int j = 0; j < NACC; j++) acc[j] = 0.f;

  float h0q[7][4];
  float h3M[5][4], h3N[5][4];
  float h5M[6][4], h5N[6][4];
  float h7M[4][4], h7N[4][4];

#pragma unroll
  for (int s = 0; s < STEPS; ++s) {
    if (s + PF < STEPS) {
      const int t    = y0 + (s + PF) - 3;
      const int trow = t < 0 ? 0 : (t >= H_ ? H_ - 1 : t);
      const float* rowp = tb + (size_t)trow * W_;
      float* dst = seg0 + ((s + PF) % RING) * PITCH;
      gl2lds16(rowp + x0 + srcA, dst + dstA);
      gl2lds4 (rowp + srcB + lane, dst + dstB);
    }
    // rows s+1..min(s+PF,13) still in flight (2 ops each); row s must be done
    waitv_imm(s + PF < STEPS ? 2 * PF : 2 * (STEPS - 1 - s));

    // a[0..11] = cols x0-4 .. x0+7 (3x ds_read_b128; 16B-aligned)
    const float4* t4 = reinterpret_cast<const float4*>(seg0 + (s % RING) * PITCH + lane * 4);
    const float4 A0 = t4[0], A1 = t4[1], A2 = t4[2];
    float a[12] = {A0.x, A0.y, A0.z, A0.w, A1.x, A1.y, A1.z, A1.w, A2.x, A2.y, A2.z, A2.w};
    if (tid == 0)   { a[0] = a[1] = a[2]  = a[3]  = a[4]; }   // x-clamp (exact, r5-verified)
    if (tid == 255) { a[8] = a[9] = a[10] = a[11] = a[7]; }

    float QM[8], QN[8];
#pragma unroll
    for (int i = 1; i <= 7; ++i) {
      QM[i] = fmaxf(fmaxf(a[i], a[i + 1]), a[i + 2]);   // v_max3
      QN[i] = fminf(fminf(a[i], a[i + 1]), a[i + 2]);   // v_min3
    }
#pragma unroll
    for (int c = 0; c < 4; ++c) {
      h0q[s % 7][c] = a[c + 4];
      h3M[s % 5][c] = QM[c + 3];
      h3N[s % 5][c] = QN[c + 3];
      h5M[s % 6][c] = fmaxf(QM[c + 2], QM[c + 4]);
      h5N[s % 6][c] = fminf(QN[c + 2], QN[c + 4]);
      h7M[s % 4][c] = fmaxf(fmaxf(QM[c + 1], QM[c + 4]), a[c + 7]);
      h7N[s % 4][c] = fminf(fminf(QN[c + 1], QN[c + 4]), a[c + 7]);
    }

    if (s >= 6) {
      const float4 pq = pv[s - 6];
      const float p[4] = {pq.x, pq.y, pq.z, pq.w};
#pragma unroll
      for (int c = 0; c < 4; ++c) {
        const float d3v = fmaxf(fmaxf(h3M[(s + 2) % 5][c], h0q[(s + 3) % 7][c]), h0q[(s + 5) % 7][c]);
        const float e3v = fminf(fminf(h3N[(s + 2) % 5][c], h0q[(s + 3) % 7][c]), h0q[(s + 5) % 7][c]);

        float d5v = fmaxf(fmaxf(h5M[(s + 3) % 6][c], h3M[(s + 1) % 5][c]), h3M[(s + 3) % 5][c]);
        d5v = fmaxf(fmaxf(d5v, h0q[(s + 2) % 7][c]), h0q[(s + 6) % 7][c]);
        float e5v = fminf(fminf(h5N[(s + 3) % 6][c], h3N[(s + 1) % 5][c]), h3N[(s + 3) % 5][c]);
        e5v = fminf(fminf(e5v, h0q[(s + 2) % 7][c]), h0q[(s + 6) % 7][c]);

        float d7v = fmaxf(fmaxf(h7M[(s + 1) % 4][c], h5M[(s + 2) % 6][c]), h5M[(s + 4) % 6][c]);
        d7v = fmaxf(fmaxf(d7v, h5M[(s + 1) % 6][c]), h5M[(s + 5) % 6][c]);
        d7v = fmaxf(fmaxf(d7v, h0q[(s + 1) % 7][c]), h0q[s % 7][c]);
        float e7v = fminf(fminf(h7N[(s + 1) % 4][c], h5N[(s + 2) % 6][c]), h5N[(s + 4) % 6][c]);
        e7v = fminf(fminf(e7v, h5N[(s + 1) % 6][c]), h5N[(s + 5) % 6][c]);
        e7v = fminf(fminf(e7v, h0q[(s + 1) % 7][c]), h0q[s % 7][c]);

        acc[0]  += p[c];
        acc[1]  += d3v;  acc[2]  = fmaf(p[c], d3v, acc[2]);
        acc[3]  += e3v;  acc[4]  = fmaf(p[c], e3v, acc[4]);
        acc[5]  += d5v;  acc[6]  = fmaf(p[c], d5v, acc[6]);
        acc[7]  += e5v;  acc[8]  = fmaf(p[c], e5v, acc[8]);
        acc[9]  += d7v;  acc[10] = fmaf(p[c], d7v, acc[10]);
        acc[11] += e7v;  acc[12] = fmaf(p[c], e7v, acc[12]);
      }
    }
  }

  // wave (64-lane) shuffle reduction, then cross-wave via LDS
#pragma unroll
  for (int j = 0; j < NACC; j++) {
    float v = acc[j];
#pragma unroll
    for (int off = 32; off > 0; off >>= 1) v += __shfl_down(v, off, 64);
    acc[j] = v;
  }
  if (lane == 0) {
#pragma unroll
    for (int j = 0; j < NACC; j++) red[wv][j] = acc[j];
  }
  __syncthreads();
  if (tid == 0) {
    const int bid = n;   // any bijective block id
#pragma unroll
    for (int j = 0; j < NACC; j++)
      partials[j * NBLK + bid] = red[0][j] + red[1][j] + red[2][j] + red[3][j];
  }
}

__global__ __launch_bounds__(256) void k_final(const float* __restrict__ partials,
                                               float* __restrict__ out) {
  const int tid = threadIdx.x;
  double acc[NACC];
#pragma unroll
  for (int j = 0; j < NACC; j++) acc[j] = 0.0;
#pragma unroll
  for (int k = 0; k < NBLK / 256; k++) {
#pragma unroll
    for (int j = 0; j < NACC; j++)
      acc[j] += (double)partials[j * NBLK + tid + k * 256];   // coalesced, independent
  }
#pragma unroll
  for (int j = 0; j < NACC; j++) {
#pragma unroll
    for (int off = 32; off > 0; off >>= 1) acc[j] += __shfl_down(acc[j], off, 64);
  }
  __shared__ double red[4][NACC];
  const int lane = tid & 63, wv = tid >> 6;
  if (lane == 0) {
#pragma unroll
    for (int j = 0; j < NACC; j++) red[wv][j] = acc[j];
  }
  __syncthreads();
  if (tid == 0) {
    double t_[NACC];
#pragma unroll
    for (int j = 0; j < NACC; j++) t_[j] = red[0][j] + red[1][j] + red[2][j] + red[3][j];
    const double Sp = t_[0];
    double total = 0.0;
#pragma unroll
    for (int k = 0; k < 3; k++) {
      const double Sd = t_[1 + 4 * k], Id = t_[2 + 4 * k];
      const double Se = t_[3 + 4 * k], Ie = t_[4 + 4 * k];
      double cd = Sp + Sd; if (cd < 1e-7) cd = 1e-7;
      double ce = Sp + Se; if (ce < 1e-7) ce = 1e-7;
      total += (1.0 - 2.0 * Id / cd) * (Sd > 0.0 ? 1.0 : 0.0);
      total += (1.0 - 2.0 * Ie / ce) * (Se > 0.0 ? 1.0 : 0.0);
    }
    out[0] = (float)(total / 3.0);
  }
}

extern "C" void kernel_launch(void* const* d_in, const int* in_sizes, int n_in,
                              void* d_out, int out_size, void* d_ws, size_t ws_size,
                              hipStream_t stream) {
  const float* pred = (const float*)d_in[0];  // pred_student_prob
  const float* tch  = (const float*)d_in[1];  // teacher_prob
  float* partials = (float*)d_ws;             // NACC * NBLK floats; fully written each launch

  k_partials<<<dim3(GX, B_), 256, 0, stream>>>(pred, tch, partials);
  k_final<<<1, 256, 0, stream>>>(partials, (float*)d_out);
}

// Round 5
// 153.701 us; speedup vs baseline: 1.9380x; 1.0435x over previous
//
#include <hip/hip_runtime.h>

// Problem constants (B, C=1, H, W) from the reference.
#define H_ 1024
#define W_ 1024
#define B_ 16
#define TH 8                   // output rows per block (STEPS=14 fully unrolls; 22 spilled - r3)
#define STEPS (TH + 6)         // input rows streamed (halo 3 each side)
#define GX (H_ / TH)           // 128 y-tiles per image
#define NBLK (GX * B_)         // 2048 blocks
#define NACC 13
#define PITCH 272              // per-wave LDS row pitch (floats): 4L | 256 | 4R | slack to 272
#define RING 12                // LDS row-ring slots per wave (>= PF+2, gcd-safe vs PF)
#define PF 10                  // prefetch depth (rows in flight)

// partials layout (SoA): partials[j * NBLK + bid]
//  j: 0=sum_pred, then k=3,5,7: {1,5,9}=sum_dil {2,6,10}=sum_p*dil
//                               {3,7,11}=sum_ero {4,8,12}=sum_p*ero

// r11 = r10 ring with DEEP prefetch (PF 4 -> 10, RING 6 -> 12).
//   r10 post-mortem: ring at PF=4 throttled per-wave MLP to ~10KB in flight
//   (vs r6 bulk's ~26KB); under device-wide load the per-request latency far
//   exceeds 4 steps of compute -> every step exposed latency; HBM BW fell
//   1.48->0.91 TB/s, VALUBusy 34->24%. The kernel is latency/queueing-bound:
//   achieved BW tracks bytes-in-flight (Little's law). Fix: PF=10 rows
//   (20 reqs ~ 25.6KB/wave, r6-level MLP) x 12 waves/CU (LDS 52.2KB ->
//   3 blocks/CU) ~ 3x r6's in-flight bytes, WITH compute overlap.
//   Counted waits: vmcnt(20) steady, 18..0 tail drain - never early-drain.
//   sched_barrier dropped: "memory" clobber already orders compiler ds_reads
//   vs the waitcnt (rule #18 is about inline-asm reads; not the case here).
//   NO __launch_bounds__ min-waves arg (r7/r9: it clamps to 64 VGPR -> spill).
// Ring slot safety: row r -> slot r%12; at step s, rows s..s+10 live; slot
//   (s+10)%12 == (s-2)%12, consumed two steps ago. OK.
// vmcnt in-order retire (m135): step-0 wait vmcnt(20) drains 8 pred loads +
//   row 0 (prologue issued rows 0..9 = 20 ops, loop adds row 10 -> 30
//   outstanding; 30-20=10 drained = 8 pred + row0's 2). Steps 1..3 drain one
//   row each; tail steps 2*(13-s).
// Algebra (verified r2): h0/h3/h5/h7 per row, output row y = t-3:
//   k3 = op(h3[y], h0[y+/-1]); k5 = op(h5[y], h3[y+/-1], h0[y+/-2]);
//   k7 = op(h7[y], h5[y+/-1], h5[y+/-2], h0[y+/-3])
// Geodesic border == clamped-index border -> exact.

__device__ __forceinline__ void gl2lds16(const float* g, float* l) {
  __builtin_amdgcn_global_load_lds(
      (const __attribute__((address_space(1))) void*)g,
      (__attribute__((address_space(3))) void*)l,
      16, 0, 0);
}
__device__ __forceinline__ void gl2lds4(const float* g, float* l) {
  __builtin_amdgcn_global_load_lds(
      (const __attribute__((address_space(1))) void*)g,
      (__attribute__((address_space(3))) void*)l,
      4, 0, 0);
}

// counted vmcnt wait; n is a compile-time constant after full unroll
__device__ __forceinline__ void waitv_imm(int n) {
  switch (n) {
    case 0:  asm volatile("s_waitcnt vmcnt(0)"  ::: "memory"); break;
    case 2:  asm volatile("s_waitcnt vmcnt(2)"  ::: "memory"); break;
    case 4:  asm volatile("s_waitcnt vmcnt(4)"  ::: "memory"); break;
    case 6:  asm volatile("s_waitcnt vmcnt(6)"  ::: "memory"); break;
    case 8:  asm volatile("s_waitcnt vmcnt(8)"  ::: "memory"); break;
    case 10: asm volatile("s_waitcnt vmcnt(10)" ::: "memory"); break;
    case 12: asm volatile("s_waitcnt vmcnt(12)" ::: "memory"); break;
    case 14: asm volatile("s_waitcnt vmcnt(14)" ::: "memory"); break;
    case 16: asm volatile("s_waitcnt vmcnt(16)" ::: "memory"); break;
    case 18: asm volatile("s_waitcnt vmcnt(18)" ::: "memory"); break;
    default: asm volatile("s_waitcnt vmcnt(20)" ::: "memory"); break;
  }
}

__global__ __launch_bounds__(256) void k_partials(const float* __restrict__ pred,
                                                  const float* __restrict__ tch,
                                                  float* __restrict__ partials) {
  __shared__ float tbuf[4 * RING * PITCH];   // 4 waves x 12 slots x 272 x 4B = 52.2KB -> 3 blocks/CU
  __shared__ float red[4][NACC];

  const int tid = threadIdx.x;
  // XCD swizzle (r6, FETCH 90->67MB): consecutive same-XCD blocks (n%8 fixed)
  // get consecutive y-tiles -> halo rows hit that XCD's L2.
  const int n     = blockIdx.y * gridDim.x + blockIdx.x;
  const int b     = n >> 7;                              // image (gridDim.x == 128)
  const int ytile = (n & 7) * 16 + ((n >> 3) & 15);      // bijective 0..127
  const int y0    = ytile * TH;
  const int x0    = tid * 4;
  const int wv    = tid >> 6;
  const int lane  = tid & 63;
  const float* tb = tch  + (size_t)b * (H_ * W_);
  const float* pb = pred + (size_t)b * (H_ * W_);

  float* seg0 = &tbuf[wv * (RING * PITCH)];

  // wave-uniform staging parameters (x-clamped at image edges; clamped-in
  // garbage floats are exactly the ones overridden by the a[] edge fixup)
  const int srcA = (wv == 0) ? 0 : -4;      // global col delta vs x0 for load A
  const int dstA = (wv == 0) ? 4 : 0;       // segment float base for load A
  const int srcB = (wv == 3) ? 960 : (wv * 256 + 204);   // absolute col, lane 0
  const int dstB = (wv == 3) ? 196 : 208;

  // ---- pred loads first (oldest in vmcnt order; retired by step 0's wait)
  float4 pv[TH];
#pragma unroll
  for (int j = 0; j < TH; ++j)
    pv[j] = *reinterpret_cast<const float4*>(pb + (size_t)(y0 + j) * W_ + x0);
  asm volatile("" ::: "memory");   // pin pred-load issue before the stage stream

  // ---- ring prologue: issue stages for rows 0..PF-1
#pragma unroll
  for (int s = 0; s < PF; ++s) {
    const int t    = y0 + s - 3;
    const int trow = t < 0 ? 0 : (t >= H_ ? H_ - 1 : t);
    const float* rowp = tb + (size_t)trow * W_;
    float* dst = seg0 + (s % RING) * PITCH;
    gl2lds16(rowp + x0 + srcA, dst + dstA);
    gl2lds4 (rowp + srcB + lane, dst + dstB);
  }

  // ---- main loop: per-step {issue stage(s+PF) || wait row s || compute row s}
  float acc[NACC];
#pragma unroll
  for (int j = 0; j < NACC; j++) acc[j] = 0.f;

  float h0q[7][4];
  float h3M[5][4], h3N[5][4];
  float h5M[6][4], h5N[6][4];
  float h7M[4][4], h7N[4][4];

#pragma unroll
  for (int s = 0; s < STEPS; ++s) {
    if (s + PF < STEPS) {
      const int t    = y0 + (s + PF) - 3;
      const int trow = t < 0 ? 0 : (t >= H_ ? H_ - 1 : t);
      const float* rowp = tb + (size_t)trow * W_;
      float* dst = seg0 + ((s + PF) % RING) * PITCH;
      gl2lds16(rowp + x0 + srcA, dst + dstA);
      gl2lds4 (rowp + srcB + lane, dst + dstB);
    }
    // rows s+1..min(s+PF,13) still in flight (2 ops each); row s must be done
    waitv_imm(s + PF < STEPS ? 2 * PF : 2 * (STEPS - 1 - s));

    // a[0..11] = cols x0-4 .. x0+7 (3x ds_read_b128; 16B-aligned)
    const float4* t4 = reinterpret_cast<const float4*>(seg0 + (s % RING) * PITCH + lane * 4);
    const float4 A0 = t4[0], A1 = t4[1], A2 = t4[2];
    float a[12] = {A0.x, A0.y, A0.z, A0.w, A1.x, A1.y, A1.z, A1.w, A2.x, A2.y, A2.z, A2.w};
    if (tid == 0)   { a[0] = a[1] = a[2]  = a[3]  = a[4]; }   // x-clamp (exact, r5-verified)
    if (tid == 255) { a[8] = a[9] = a[10] = a[11] = a[7]; }

    float QM[8], QN[8];
#pragma unroll
    for (int i = 1; i <= 7; ++i) {
      QM[i] = fmaxf(fmaxf(a[i], a[i + 1]), a[i + 2]);   // v_max3
      QN[i] = fminf(fminf(a[i], a[i + 1]), a[i + 2]);   // v_min3
    }
#pragma unroll
    for (int c = 0; c < 4; ++c) {
      h0q[s % 7][c] = a[c + 4];
      h3M[s % 5][c] = QM[c + 3];
      h3N[s % 5][c] = QN[c + 3];
      h5M[s % 6][c] = fmaxf(QM[c + 2], QM[c + 4]);
      h5N[s % 6][c] = fminf(QN[c + 2], QN[c + 4]);
      h7M[s % 4][c] = fmaxf(fmaxf(QM[c + 1], QM[c + 4]), a[c + 7]);
      h7N[s % 4][c] = fminf(fminf(QN[c + 1], QN[c + 4]), a[c + 7]);
    }

    if (s >= 6) {
      const float4 pq = pv[s - 6];
      const float p[4] = {pq.x, pq.y, pq.z, pq.w};
#pragma unroll
      for (int c = 0; c < 4; ++c) {
        const float d3v = fmaxf(fmaxf(h3M[(s + 2) % 5][c], h0q[(s + 3) % 7][c]), h0q[(s + 5) % 7][c]);
        const float e3v = fminf(fminf(h3N[(s + 2) % 5][c], h0q[(s + 3) % 7][c]), h0q[(s + 5) % 7][c]);

        float d5v = fmaxf(fmaxf(h5M[(s + 3) % 6][c], h3M[(s + 1) % 5][c]), h3M[(s + 3) % 5][c]);
        d5v = fmaxf(fmaxf(d5v, h0q[(s + 2) % 7][c]), h0q[(s + 6) % 7][c]);
        float e5v = fminf(fminf(h5N[(s + 3) % 6][c], h3N[(s + 1) % 5][c]), h3N[(s + 3) % 5][c]);
        e5v = fminf(fminf(e5v, h0q[(s + 2) % 7][c]), h0q[(s + 6) % 7][c]);

        float d7v = fmaxf(fmaxf(h7M[(s + 1) % 4][c], h5M[(s + 2) % 6][c]), h5M[(s + 4) % 6][c]);
        d7v = fmaxf(fmaxf(d7v, h5M[(s + 1) % 6][c]), h5M[(s + 5) % 6][c]);
        d7v = fmaxf(fmaxf(d7v, h0q[(s + 1) % 7][c]), h0q[s % 7][c]);
        float e7v = fminf(fminf(h7N[(s + 1) % 4][c], h5N[(s + 2) % 6][c]), h5N[(s + 4) % 6][c]);
        e7v = fminf(fminf(e7v, h5N[(s + 1) % 6][c]), h5N[(s + 5) % 6][c]);
        e7v = fminf(fminf(e7v, h0q[(s + 1) % 7][c]), h0q[s % 7][c]);

        acc[0]  += p[c];
        acc[1]  += d3v;  acc[2]  = fmaf(p[c], d3v, acc[2]);
        acc[3]  += e3v;  acc[4]  = fmaf(p[c], e3v, acc[4]);
        acc[5]  += d5v;  acc[6]  = fmaf(p[c], d5v, acc[6]);
        acc[7]  += e5v;  acc[8]  = fmaf(p[c], e5v, acc[8]);
        acc[9]  += d7v;  acc[10] = fmaf(p[c], d7v, acc[10]);
        acc[11] += e7v;  acc[12] = fmaf(p[c], e7v, acc[12]);
      }
    }
  }

  // wave (64-lane) shuffle reduction, then cross-wave via LDS
#pragma unroll
  for (int j = 0; j < NACC; j++) {
    float v = acc[j];
#pragma unroll
    for (int off = 32; off > 0; off >>= 1) v += __shfl_down(v, off, 64);
    acc[j] = v;
  }
  if (lane == 0) {
#pragma unroll
    for (int j = 0; j < NACC; j++) red[wv][j] = acc[j];
  }
  __syncthreads();
  if (tid == 0) {
    const int bid = n;   // any bijective block id
#pragma unroll
    for (int j = 0; j < NACC; j++)
      partials[j * NBLK + bid] = red[0][j] + red[1][j] + red[2][j] + red[3][j];
  }
}

__global__ __launch_bounds__(256) void k_final(const float* __restrict__ partials,
                                               float* __restrict__ out) {
  const int tid = threadIdx.x;
  double acc[NACC];
#pragma unroll
  for (int j = 0; j < NACC; j++) acc[j] = 0.0;
#pragma unroll
  for (int k = 0; k < NBLK / 256; k++) {
#pragma unroll
    for (int j = 0; j < NACC; j++)
      acc[j] += (double)partials[j * NBLK + tid + k * 256];   // coalesced, independent
  }
#pragma unroll
  for (int j = 0; j < NACC; j++) {
#pragma unroll
    for (int off = 32; off > 0; off >>= 1) acc[j] += __shfl_down(acc[j], off, 64);
  }
  __shared__ double red[4][NACC];
  const int lane = tid & 63, wv = tid >> 6;
  if (lane == 0) {
#pragma unroll
    for (int j = 0; j < NACC; j++) red[wv][j] = acc[j];
  }
  __syncthreads();
  if (tid == 0) {
    double t_[NACC];
#pragma unroll
    for (int j = 0; j < NACC; j++) t_[j] = red[0][j] + red[1][j] + red[2][j] + red[3][j];
    const double Sp = t_[0];
    double total = 0.0;
#pragma unroll
    for (int k = 0; k < 3; k++) {
      const double Sd = t_[1 + 4 * k], Id = t_[2 + 4 * k];
      const double Se = t_[3 + 4 * k], Ie = t_[4 + 4 * k];
      double cd = Sp + Sd; if (cd < 1e-7) cd = 1e-7;
      double ce = Sp + Se; if (ce < 1e-7) ce = 1e-7;
      total += (1.0 - 2.0 * Id / cd) * (Sd > 0.0 ? 1.0 : 0.0);
      total += (1.0 - 2.0 * Ie / ce) * (Se > 0.0 ? 1.0 : 0.0);
    }
    out[0] = (float)(total / 3.0);
  }
}

extern "C" void kernel_launch(void* const* d_in, const int* in_sizes, int n_in,
                              void* d_out, int out_size, void* d_ws, size_t ws_size,
                              hipStream_t stream) {
  const float* pred = (const float*)d_in[0];  // pred_student_prob
  const float* tch  = (const float*)d_in[1];  // teacher_prob
  float* partials = (float*)d_ws;             // NACC * NBLK floats; fully written each launch

  k_partials<<<dim3(GX, B_), 256, 0, stream>>>(pred, tch, partials);
  k_final<<<1, 256, 0, stream>>>(partials, (float*)d_out);
}